// Round 7
// baseline (280.609 us; speedup 1.0000x reference)
//
#include <hip/hip_runtime.h>
#include <hip/hip_bf16.h>
#include <math.h>

#define DIM 128
#define NHEAD 8
#define DHEAD 16
#define HID 512
#define LN_EPS 1e-5f
// (1/sqrt(128))*log2(e) folded into q so softmax runs in exp2 domain
#define QSCALE 0.12751879104863297f

typedef __bf16 bf16x8 __attribute__((ext_vector_type(8)));
typedef float f32x4 __attribute__((ext_vector_type(4)));
typedef float f32x2 __attribute__((ext_vector_type(2)));
typedef _Float16 f16x2 __attribute__((ext_vector_type(2)));

__device__ inline float bf2f(unsigned int bits16) {
    return __uint_as_float(bits16 << 16);
}
__device__ inline unsigned short f2bf(float f) {
    unsigned int u = __float_as_uint(f);
    unsigned int r = u + 0x7fff + ((u >> 16) & 1);   // RNE
    return (unsigned short)(r >> 16);
}
__device__ inline unsigned short f2h(float f) {
    _Float16 h = (_Float16)f;
    return __builtin_bit_cast(unsigned short, h);
}
// pack two floats -> two OCP e4m3 bytes (low ushort)
__device__ inline unsigned short pk_fp8(float a, float b) {
    int r = __builtin_amdgcn_cvt_pk_fp8_f32(a, b, 0, false);
    return (unsigned short)(r & 0xffff);
}
// unpack 2 fp8 bytes; HI=false: bytes 0,1; HI=true: bytes 2,3 (template -> immediate)
template <bool HI>
__device__ inline f32x2 unpk_fp8(unsigned int w) {
    return __builtin_amdgcn_cvt_pk_f32_fp8((int)w, HI);
}
__device__ inline float fexp2(float x) { return __builtin_amdgcn_exp2f(x); }

// async global->LDS, 16B per lane
__device__ inline void gload_lds16(const void* g, void* l) {
    __builtin_amdgcn_global_load_lds(
        (const __attribute__((address_space(1))) unsigned int*)g,
        (__attribute__((address_space(3))) unsigned int*)l, 16, 0, 0);
}

// ---------------- fused prep: zero counts + feat->bf16 + weight transposes ----------------
__global__ __launch_bounds__(256) void prep_kernel(
        int* counts, int Nn,
        const float* __restrict__ feat, unsigned short* __restrict__ featb,
        const float* __restrict__ Wq, const float* __restrict__ Wk, const float* __restrict__ Wv,
        unsigned short* __restrict__ Wqkvt,
        const float* __restrict__ W1, unsigned short* __restrict__ W1t,
        const float* __restrict__ W2, unsigned short* __restrict__ W2t,
        int zb, int fb) {
    int blk = blockIdx.x, t = threadIdx.x;
    if (blk < zb) {
        int i = blk * 1024 + t * 4;
        if (i < Nn) *(int4*)(counts + i) = make_int4(0, 0, 0, 0);
    } else if (blk < fb) {
        int i = (blk - zb) * 256 + t;
        if (i < Nn * 32) {
            float4 v = *(const float4*)(feat + (size_t)i * 4);
            ushort4 o;
            o.x = f2bf(v.x); o.y = f2bf(v.y); o.z = f2bf(v.z); o.w = f2bf(v.w);
            *(ushort4*)(featb + (size_t)i * 4) = o;
        }
    } else {
        int b2_ = blk - fb;
        if (b2_ < 192) {
            int sec = b2_ >> 6;
            const float* W = sec == 0 ? Wq : (sec == 1 ? Wk : Wv);
            int o = (b2_ & 63) * 256 + t;
            int oc = o >> 7, orow = o & 127;
            Wqkvt[sec * 16384 + o] = f2bf(W[(size_t)orow * 128 + oc]);
        } else if (b2_ < 448) {
            int o = (b2_ - 192) * 256 + t;
            int oc = o >> 7, orow = o & 127;
            W1t[o] = f2bf(W1[(size_t)orow * 512 + oc]);
        } else {
            int o = (b2_ - 448) * 256 + t;
            int oc = o >> 9, orow = o & 511;
            W2t[o] = f2bf(W2[(size_t)orow * 128 + oc]);
        }
    }
}

// ---------------- CSR build ----------------

__global__ void count_kernel(const int* __restrict__ dst, int* counts, int E) {
    int e = blockIdx.x * blockDim.x + threadIdx.x;
    if (e < E) atomicAdd(&counts[dst[e]], 1);
}

__global__ __launch_bounds__(256) void scanA_kernel(const int* __restrict__ counts, int* bsum, int Nn) {
    int blk = blockIdx.x, t = threadIdx.x;
    int i = blk * 1024 + t * 4;
    int s = 0;
    if (i < Nn) { int4 x = *(const int4*)(counts + i); s = x.x + x.y + x.z + x.w; }
#pragma unroll
    for (int off = 1; off < 64; off <<= 1) s += __shfl_xor(s, off, 64);
    __shared__ int wt[4];
    if ((t & 63) == 0) wt[t >> 6] = s;
    __syncthreads();
    if (t == 0) bsum[blk] = wt[0] + wt[1] + wt[2] + wt[3];
}

__global__ __launch_bounds__(256) void scanC_kernel(int* counts, const int* __restrict__ bsum,
                                                    int* offsets, int Nn, int NCH) {
    int blk = blockIdx.x, t = threadIdx.x, lane = t & 63, wv = t >> 6;
    __shared__ int wt[4];
    __shared__ int base_s;
    if (wv == 0) {
        int v = (lane < NCH) ? bsum[lane] : 0;
        int s = v;
#pragma unroll
        for (int off = 1; off < 64; off <<= 1) {
            int u = __shfl_up(s, off, 64);
            if (lane >= off) s += u;
        }
        int basev = (blk > 0) ? __shfl(s, blk - 1, 64) : 0;
        int tot = __shfl(s, NCH - 1, 64);
        if (lane == 0) {
            base_s = basev;
            if (blk == 0) offsets[Nn] = tot;
        }
    }
    int i = blk * 1024 + t * 4;
    int4 x = make_int4(0, 0, 0, 0);
    if (i < Nn) x = *(const int4*)(counts + i);
    int ts = x.x + x.y + x.z + x.w;
    int s = ts;
#pragma unroll
    for (int off = 1; off < 64; off <<= 1) {
        int u = __shfl_up(s, off, 64);
        if (lane >= off) s += u;
    }
    if (lane == 63) wt[wv] = s;
    __syncthreads();
    int woff = 0;
    for (int wi = 0; wi < wv; ++wi) woff += wt[wi];
    int excl = base_s + woff + (s - ts);
    if (i < Nn) {
        int o0 = excl, o1 = o0 + x.x, o2 = o1 + x.y, o3 = o2 + x.z;
        *(int4*)(offsets + i) = make_int4(o0, o1, o2, o3);
        *(int4*)(counts + i) = make_int4(o0, o1, o2, o3);
    }
}

__global__ void fill_kernel(const int* __restrict__ dst, const int* __restrict__ src,
                            int* cursor, int* srcs, int E) {
    int e = blockIdx.x * blockDim.x + threadIdx.x;
    if (e < E) {
        int pos = atomicAdd(&cursor[dst[e]], 1);
        srcs[pos] = src[e];
    }
}

// ---------------- qkv GEMM -> f16 q (pre-scaled), fp8-packed kv table ----------------
// grid (3, MP/128): region 0:q 1:k 2:v.
// kvp word (per node, per lane l): bytes [k(2l),k(2l+1),v(2l),v(2l+1)] (e4m3)
#define QST 136
__global__ __launch_bounds__(256) void qkv_gemm(
        const unsigned short* __restrict__ A, const unsigned short* __restrict__ Bt,
        unsigned short* __restrict__ qb, unsigned short* __restrict__ kvp) {
    __shared__ unsigned short smem[128 * QST];
    unsigned short* As = smem;
    unsigned short* Bs = smem + 4096;
    int t = threadIdx.x;
    int wave = t >> 6, lane = t & 63;
    int wr = wave >> 1, wc = wave & 1;
    int lrow = lane & 15, kq = lane >> 4;
    int m0 = blockIdx.y * 128;
    int region = blockIdx.x;
    int n0 = region * 128;
    int srow = t >> 2, scol8 = (t & 3) * 8;

    f32x4 acc[4][4] = {};
    for (int k0 = 0; k0 < 128; k0 += 32) {
        gload_lds16(A + (size_t)(m0 + srow) * 128 + k0 + scol8,      As + t * 8);
        gload_lds16(A + (size_t)(m0 + 64 + srow) * 128 + k0 + scol8, As + 2048 + t * 8);
        gload_lds16(Bt + (size_t)(n0 + srow) * 128 + k0 + scol8,      Bs + t * 8);
        gload_lds16(Bt + (size_t)(n0 + 64 + srow) * 128 + k0 + scol8, Bs + 2048 + t * 8);
        __syncthreads();
        bf16x8 af[4], bfr[4];
#pragma unroll
        for (int mi = 0; mi < 4; ++mi)
            af[mi] = *(const bf16x8*)(&As[(wr * 64 + mi * 16 + lrow) * 32 + kq * 8]);
#pragma unroll
        for (int ni = 0; ni < 4; ++ni)
            bfr[ni] = *(const bf16x8*)(&Bs[(wc * 64 + ni * 16 + lrow) * 32 + kq * 8]);
#pragma unroll
        for (int mi = 0; mi < 4; ++mi)
#pragma unroll
            for (int ni = 0; ni < 4; ++ni)
                acc[mi][ni] = __builtin_amdgcn_mfma_f32_16x16x32_bf16(af[mi], bfr[ni], acc[mi][ni], 0, 0, 0);
        __syncthreads();
    }

    float scale = (region == 0) ? QSCALE : 1.f;
#pragma unroll
    for (int ni = 0; ni < 4; ++ni) {
        int col = wc * 64 + ni * 16 + lrow;
#pragma unroll
        for (int mi = 0; mi < 4; ++mi) {
#pragma unroll
            for (int r = 0; r < 4; ++r) {
                int row = wr * 64 + mi * 16 + kq * 4 + r;
                smem[row * QST + col] = f2h(acc[mi][ni][r] * scale);
            }
        }
    }
    __syncthreads();
    if (region == 0) {
        unsigned short* outp = qb + (size_t)m0 * 128;
#pragma unroll
        for (int i = 0; i < 8; ++i) {
            int chunk = i * 256 + t;
            int row = chunk >> 4, c16 = chunk & 15;
            *(float4*)(outp + (size_t)chunk * 8) = *(const float4*)(smem + row * QST + c16 * 8);
        }
    } else {
        int off = region - 1;                 // 0: k bytes, 1: v bytes
        int row = t >> 1, half = t & 1;
        unsigned short* dstp = kvp + (size_t)(m0 + row) * 128 + off;
        const unsigned short* sp = smem + row * QST;
#pragma unroll
        for (int jj = 0; jj < 32; ++jj) {
            int j = half * 32 + jj;
            float f0 = (float)__builtin_bit_cast(_Float16, sp[2 * j]);
            float f1 = (float)__builtin_bit_cast(_Float16, sp[2 * j + 1]);
            dstp[2 * j] = pk_fp8(f0, f1);
        }
    }
}

// ---------------- fused attention aggregate + residual + LN1 ----------------
// one wave per node, 2 dims/lane; ONE dword gather per edge (fp8 k pair + v pair)
__global__ __launch_bounds__(256) void agg_ln1_kernel(
        const unsigned short* __restrict__ qb, const unsigned short* __restrict__ kvp,
        const float* __restrict__ feat,
        const int* __restrict__ srcs, const int* __restrict__ offsets,
        const float* __restrict__ g, const float* __restrict__ b,
        unsigned short* __restrict__ rstb, int n) {
    int node = blockIdx.x * 4 + (threadIdx.x >> 6);
    int lane = threadIdx.x & 63;
    if (node >= n) return;

    unsigned int qw = ((const unsigned int*)qb)[(size_t)node * 64 + lane];
    f16x2 qp = __builtin_bit_cast(f16x2, qw);
    float q0 = (float)qp.x, q1 = (float)qp.y;
    const unsigned int* kv32 = (const unsigned int*)kvp;   // node stride 64 words

    int beg = offsets[node], end = offsets[node + 1];
    float m = -INFINITY, l = 0.f, a0 = 0.f, a1 = 0.f;

    int idx = beg;
    for (; idx + 8 <= end; idx += 8) {
        int s[8];
#pragma unroll
        for (int i = 0; i < 8; ++i) s[i] = srcs[idx + i];
        unsigned int w[8];
#pragma unroll
        for (int i = 0; i < 8; ++i) w[i] = kv32[(size_t)s[i] * 64 + lane];
        float sc[8];
#pragma unroll
        for (int i = 0; i < 8; ++i) {
            f32x2 kk = unpk_fp8<false>(w[i]);
            float p = fmaf(kk.x, q0, kk.y * q1);
            p += __shfl_xor(p, 1, 8);
            p += __shfl_xor(p, 2, 8);
            p += __shfl_xor(p, 4, 8);
            sc[i] = p;
        }
        float mn = m;
#pragma unroll
        for (int i = 0; i < 8; ++i) mn = fmaxf(mn, sc[i]);
        float f = fexp2(m - mn);
        float wsum = 0.f, d0 = 0.f, d1 = 0.f;
#pragma unroll
        for (int i = 0; i < 8; ++i) {
            float ww = fexp2(sc[i] - mn);
            f32x2 vv = unpk_fp8<true>(w[i]);
            wsum += ww;
            d0 = fmaf(vv.x, ww, d0);
            d1 = fmaf(vv.y, ww, d1);
        }
        l = l * f + wsum;
        a0 = a0 * f + d0;
        a1 = a1 * f + d1;
        m = mn;
    }
    for (; idx < end; ++idx) {
        int s = srcs[idx];
        unsigned int w = kv32[(size_t)s * 64 + lane];
        f32x2 kk = unpk_fp8<false>(w);
        float p = fmaf(kk.x, q0, kk.y * q1);
        p += __shfl_xor(p, 1, 8);
        p += __shfl_xor(p, 2, 8);
        p += __shfl_xor(p, 4, 8);
        float mn = fmaxf(m, p);
        float f = fexp2(m - mn), ww = fexp2(p - mn);
        f32x2 vv = unpk_fp8<true>(w);
        l = l * f + ww;
        a0 = a0 * f + ww * vv.x;
        a1 = a1 * f + ww * vv.y;
        m = mn;
    }

    float inv = (l > 0.f) ? 1.f / l : 0.f;
    float2 fv = *(const float2*)(feat + (size_t)node * DIM + 2 * lane);
    float x0 = a0 * inv + fv.x;
    float x1 = a1 * inv + fv.y;

    float s1 = x0 + x1;
    float s2 = x0 * x0 + x1 * x1;
#pragma unroll
    for (int off = 1; off < 64; off <<= 1) {
        s1 += __shfl_xor(s1, off, 64);
        s2 += __shfl_xor(s2, off, 64);
    }
    float mean = s1 * (1.f / DIM);
    float var = s2 * (1.f / DIM) - mean * mean;
    float rinv = rsqrtf(var + LN_EPS);
    float g0 = g[2 * lane], g1 = g[2 * lane + 1];
    float b0 = b[2 * lane], b1 = b[2 * lane + 1];
    float o0 = (x0 - mean) * rinv * g0 + b0;
    float o1 = (x1 - mean) * rinv * g1 + b1;
    unsigned int packed = (unsigned int)f2bf(o0) | ((unsigned int)f2bf(o1) << 16);
    ((unsigned int*)rstb)[(size_t)node * 64 + lane] = packed;
}

// ---------------- FFN1: hid = PReLU(rst @ W1 + b1), bf16 out ----------------
// grid (4, MP/128); m97-style 128x128 tile, K=128; LDS-staged coalesced stores
__global__ __launch_bounds__(256) void ffn1_gemm(
        const unsigned short* __restrict__ A, const unsigned short* __restrict__ Bt,
        unsigned short* __restrict__ hid,
        const float* __restrict__ b1, const float* __restrict__ prelu) {
    __shared__ unsigned short smem[128 * QST];
    unsigned short* As = smem;
    unsigned short* Bs = smem + 4096;
    int t = threadIdx.x;
    int wave = t >> 6, lane = t & 63;
    int wr = wave >> 1, wc = wave & 1;
    int lrow = lane & 15, kq = lane >> 4;
    int m0 = blockIdx.y * 128;
    int n0 = blockIdx.x * 128;
    int srow = t >> 2, scol8 = (t & 3) * 8;

    f32x4 acc[4][4] = {};
    for (int k0 = 0; k0 < 128; k0 += 32) {
        gload_lds16(A + (size_t)(m0 + srow) * 128 + k0 + scol8,      As + t * 8);
        gload_lds16(A + (size_t)(m0 + 64 + srow) * 128 + k0 + scol8, As + 2048 + t * 8);
        gload_lds16(Bt + (size_t)(n0 + srow) * 128 + k0 + scol8,      Bs + t * 8);
        gload_lds16(Bt + (size_t)(n0 + 64 + srow) * 128 + k0 + scol8, Bs + 2048 + t * 8);
        __syncthreads();
        bf16x8 af[4], bfr[4];
#pragma unroll
        for (int mi = 0; mi < 4; ++mi)
            af[mi] = *(const bf16x8*)(&As[(wr * 64 + mi * 16 + lrow) * 32 + kq * 8]);
#pragma unroll
        for (int ni = 0; ni < 4; ++ni)
            bfr[ni] = *(const bf16x8*)(&Bs[(wc * 64 + ni * 16 + lrow) * 32 + kq * 8]);
#pragma unroll
        for (int mi = 0; mi < 4; ++mi)
#pragma unroll
            for (int ni = 0; ni < 4; ++ni)
                acc[mi][ni] = __builtin_amdgcn_mfma_f32_16x16x32_bf16(af[mi], bfr[ni], acc[mi][ni], 0, 0, 0);
        __syncthreads();
    }

#pragma unroll
    for (int ni = 0; ni < 4; ++ni) {
        int col = wc * 64 + ni * 16 + lrow;
        int cg = n0 + col;
        float biv = b1[cg], pwv = prelu[cg];
#pragma unroll
        for (int mi = 0; mi < 4; ++mi) {
#pragma unroll
            for (int r = 0; r < 4; ++r) {
                int row = wr * 64 + mi * 16 + kq * 4 + r;
                float v = acc[mi][ni][r] + biv;
                v = v >= 0.f ? v : pwv * v;
                smem[row * QST + col] = f2bf(v);
            }
        }
    }
    __syncthreads();
#pragma unroll
    for (int i = 0; i < 8; ++i) {
        int chunk = i * 256 + t;
        int row = chunk >> 4, c16 = chunk & 15;
        *(float4*)(hid + (size_t)(m0 + row) * 512 + n0 + c16 * 8) =
            *(const float4*)(smem + row * QST + c16 * 8);
    }
}

// ---------------- FFN2 + residual + LN2: out = LN(hid @ W2 + b2 + rst) ----------------
// grid (MP/128); K=512, 16 k-iters
__global__ __launch_bounds__(256) void ffn2_ln2_kernel(
        const unsigned short* __restrict__ hid, const unsigned short* __restrict__ W2t,
        const unsigned short* __restrict__ rstb,
        const float* __restrict__ b2, const float* __restrict__ g, const float* __restrict__ bb,
        float* __restrict__ out, int Nn) {
    __shared__ unsigned short As[128 * 32];
    __shared__ unsigned short Bs[128 * 32];
    __shared__ float red[128][4];
    int t = threadIdx.x;
    int wave = t >> 6, lane = t & 63;
    int wr = wave >> 1, wc = wave & 1;
    int lrow = lane & 15, kq = lane >> 4;
    int m0 = blockIdx.x * 128;
    int srow = t >> 2, scol8 = (t & 3) * 8;

    f32x4 acc[4][4] = {};
    for (int k0 = 0; k0 < 512; k0 += 32) {
        gload_lds16(hid + (size_t)(m0 + srow) * 512 + k0 + scol8,      As + t * 8);
        gload_lds16(hid + (size_t)(m0 + 64 + srow) * 512 + k0 + scol8, As + 2048 + t * 8);
        gload_lds16(W2t + (size_t)srow * 512 + k0 + scol8,             Bs + t * 8);
        gload_lds16(W2t + (size_t)(64 + srow) * 512 + k0 + scol8,      Bs + 2048 + t * 8);
        __syncthreads();
        bf16x8 af[4], bfr[4];
#pragma unroll
        for (int mi = 0; mi < 4; ++mi)
            af[mi] = *(const bf16x8*)(&As[(wr * 64 + mi * 16 + lrow) * 32 + kq * 8]);
#pragma unroll
        for (int ni = 0; ni < 4; ++ni)
            bfr[ni] = *(const bf16x8*)(&Bs[(wc * 64 + ni * 16 + lrow) * 32 + kq * 8]);
#pragma unroll
        for (int mi = 0; mi < 4; ++mi)
#pragma unroll
            for (int ni = 0; ni < 4; ++ni)
                acc[mi][ni] = __builtin_amdgcn_mfma_f32_16x16x32_bf16(af[mi], bfr[ni], acc[mi][ni], 0, 0, 0);
        __syncthreads();
    }

    float b2v[4], gv[4], bv[4];
    int cols[4];
#pragma unroll
    for (int ni = 0; ni < 4; ++ni) {
        cols[ni] = wc * 64 + ni * 16 + lrow;
        b2v[ni] = b2[cols[ni]]; gv[ni] = g[cols[ni]]; bv[ni] = bb[cols[ni]];
    }
#pragma unroll
    for (int mi = 0; mi < 4; ++mi) {
#pragma unroll
        for (int r = 0; r < 4; ++r) {
            int rloc = wr * 64 + mi * 16 + kq * 4 + r;
            int row = m0 + rloc;
            float ps = 0.f, pq = 0.f;
#pragma unroll
            for (int ni = 0; ni < 4; ++ni) {
                float rsv = bf2f(rstb[(size_t)row * 128 + cols[ni]]);
                float v = acc[mi][ni][r] + b2v[ni] + rsv;
                acc[mi][ni][r] = v;
                ps += v; pq += v * v;
            }
#pragma unroll
            for (int off = 1; off < 16; off <<= 1) {
                ps += __shfl_xor(ps, off, 16);
                pq += __shfl_xor(pq, off, 16);
            }
            if (lrow == 0) { red[rloc][wc * 2] = ps; red[rloc][wc * 2 + 1] = pq; }
        }
    }
    __syncthreads();
#pragma unroll
    for (int mi = 0; mi < 4; ++mi) {
#pragma unroll
        for (int r = 0; r < 4; ++r) {
            int rloc = wr * 64 + mi * 16 + kq * 4 + r;
            int row = m0 + rloc;
            float s1 = red[rloc][0] + red[rloc][2];
            float s2 = red[rloc][1] + red[rloc][3];
            float mean = s1 * (1.f / DIM);
            float var = s2 * (1.f / DIM) - mean * mean;
            float rs = rsqrtf(var + LN_EPS);
            if (row < Nn) {
#pragma unroll
                for (int ni = 0; ni < 4; ++ni)
                    out[(size_t)row * 128 + cols[ni]] =
                        (acc[mi][ni][r] - mean) * rs * gv[ni] + bv[ni];
            }
        }
    }
}

// ---------------- launch ----------------

extern "C" void kernel_launch(void* const* d_in, const int* in_sizes, int n_in,
                              void* d_out, int out_size, void* d_ws, size_t ws_size,
                              hipStream_t stream) {
    const float* feat   = (const float*)d_in[0];
    const int*   src    = (const int*)d_in[1];
    const int*   dst    = (const int*)d_in[2];
    const float* Wq     = (const float*)d_in[3];
    const float* Wk     = (const float*)d_in[4];
    const float* Wv     = (const float*)d_in[5];
    const float* ln1_g  = (const float*)d_in[6];
    const float* ln1_b  = (const float*)d_in[7];
    const float* ln2_g  = (const float*)d_in[8];
    const float* ln2_b  = (const float*)d_in[9];
    const float* W1     = (const float*)d_in[10];
    const float* b1     = (const float*)d_in[11];
    const float* prelu  = (const float*)d_in[12];
    const float* W2     = (const float*)d_in[13];
    const float* b2     = (const float*)d_in[14];
    float* out = (float*)d_out;

    const int Nn = in_sizes[0] / DIM;        // 40000
    const int E  = in_sizes[1];              // 640000
    const int MP = (Nn + 127) & ~127;        // 40064

    char* w = (char*)d_ws;
    unsigned short* qb   = (unsigned short*)w; w += (size_t)MP * DIM * 2;
    unsigned short* kvp  = (unsigned short*)w; w += (size_t)MP * DIM * 2;  // fp8-packed k|v
    unsigned short* rstb = (unsigned short*)w; w += (size_t)MP * DIM * 2;
    unsigned short* featb= (unsigned short*)w; w += (size_t)MP * DIM * 2;
    unsigned short* hid  = (unsigned short*)w; w += (size_t)MP * HID * 2;
    unsigned short* Wqkvt= (unsigned short*)w; w += 3 * DIM * DIM * 2;
    unsigned short* W1t  = (unsigned short*)w; w += (size_t)HID * DIM * 2;
    unsigned short* W2t  = (unsigned short*)w; w += (size_t)DIM * HID * 2;
    int* counts  = (int*)w;  w += (size_t)Nn * 4;
    int* offsets = (int*)w;  w += (size_t)(Nn + 4) * 4;
    int* bsum    = (int*)w;  w += 64 * 4;
    int* srcs    = (int*)w;

    const int NCH = (Nn + 1023) / 1024;      // 40 (<= 64)
    const int zb = NCH;
    const int fb = zb + Nn / 8;

    prep_kernel<<<fb + 192 + 256 + 256, 256, 0, stream>>>(
        counts, Nn, feat, featb, Wq, Wk, Wv, Wqkvt, W1, W1t, W2, W2t, zb, fb);

    count_kernel<<<(E + 255) / 256, 256, 0, stream>>>(dst, counts, E);
    scanA_kernel<<<NCH, 256, 0, stream>>>(counts, bsum, Nn);
    scanC_kernel<<<NCH, 256, 0, stream>>>(counts, bsum, offsets, Nn, NCH);
    fill_kernel<<<(E + 255) / 256, 256, 0, stream>>>(dst, src, counts, srcs, E);

    {
        dim3 grid(3, MP / 128);
        qkv_gemm<<<grid, 256, 0, stream>>>(featb, Wqkvt, qb, kvp);
    }

    agg_ln1_kernel<<<(Nn + 3) / 4, 256, 0, stream>>>(qb, kvp, feat, srcs, offsets,
                                                     ln1_g, ln1_b, rstb, Nn);

    {
        dim3 grid(4, MP / 128);
        ffn1_gemm<<<grid, 256, 0, stream>>>(rstb, W1t, hid, b1, prelu);
    }

    ffn2_ln2_kernel<<<MP / 128, 256, 0, stream>>>(hid, W2t, rstb, b2, ln2_g, ln2_b, out, Nn);
}

// Round 9
// 279.237 us; speedup vs baseline: 1.0049x; 1.0049x over previous
//
#include <hip/hip_runtime.h>
#include <hip/hip_bf16.h>
#include <math.h>

#define DIM 128
#define NHEAD 8
#define DHEAD 16
#define HID 512
#define LN_EPS 1e-5f
// (1/sqrt(128))*log2(e) folded into q so softmax runs in exp2 domain
#define QSCALE 0.12751879104863297f

typedef __bf16 bf16x8 __attribute__((ext_vector_type(8)));
typedef float f32x4 __attribute__((ext_vector_type(4)));
typedef float f32x2 __attribute__((ext_vector_type(2)));
typedef _Float16 f16x2 __attribute__((ext_vector_type(2)));

__device__ inline float bf2f(unsigned int bits16) {
    return __uint_as_float(bits16 << 16);
}
__device__ inline unsigned short f2bf(float f) {
    unsigned int u = __float_as_uint(f);
    unsigned int r = u + 0x7fff + ((u >> 16) & 1);   // RNE
    return (unsigned short)(r >> 16);
}
__device__ inline unsigned short f2h(float f) {
    _Float16 h = (_Float16)f;
    return __builtin_bit_cast(unsigned short, h);
}
// pack two floats -> two OCP e4m3 bytes (low ushort)
__device__ inline unsigned short pk_fp8(float a, float b) {
    int r = __builtin_amdgcn_cvt_pk_fp8_f32(a, b, 0, false);
    return (unsigned short)(r & 0xffff);
}
// unpack 2 fp8 bytes; HI=false: bytes 0,1; HI=true: bytes 2,3 (template -> immediate)
template <bool HI>
__device__ inline f32x2 unpk_fp8(unsigned int w) {
    return __builtin_amdgcn_cvt_pk_f32_fp8((int)w, HI);
}
__device__ inline float fexp2(float x) { return __builtin_amdgcn_exp2f(x); }

// async global->LDS, 16B per lane
__device__ inline void gload_lds16(const void* g, void* l) {
    __builtin_amdgcn_global_load_lds(
        (const __attribute__((address_space(1))) unsigned int*)g,
        (__attribute__((address_space(3))) unsigned int*)l, 16, 0, 0);
}

// ---------------- fused prep: zero counts + feat->bf16 + weight transposes ----------------
__global__ __launch_bounds__(256) void prep_kernel(
        int* counts, int Nn,
        const float* __restrict__ feat, unsigned short* __restrict__ featb,
        const float* __restrict__ Wq, const float* __restrict__ Wk, const float* __restrict__ Wv,
        unsigned short* __restrict__ Wqkvt,
        const float* __restrict__ W1, unsigned short* __restrict__ W1t,
        const float* __restrict__ W2, unsigned short* __restrict__ W2t,
        int zb, int fb) {
    int blk = blockIdx.x, t = threadIdx.x;
    if (blk < zb) {
        int i = blk * 1024 + t * 4;
        if (i < Nn) *(int4*)(counts + i) = make_int4(0, 0, 0, 0);
    } else if (blk < fb) {
        int i = (blk - zb) * 256 + t;
        if (i < Nn * 32) {
            float4 v = *(const float4*)(feat + (size_t)i * 4);
            ushort4 o;
            o.x = f2bf(v.x); o.y = f2bf(v.y); o.z = f2bf(v.z); o.w = f2bf(v.w);
            *(ushort4*)(featb + (size_t)i * 4) = o;
        }
    } else {
        int b2_ = blk - fb;
        if (b2_ < 192) {
            int sec = b2_ >> 6;
            const float* W = sec == 0 ? Wq : (sec == 1 ? Wk : Wv);
            int o = (b2_ & 63) * 256 + t;
            int oc = o >> 7, orow = o & 127;
            Wqkvt[sec * 16384 + o] = f2bf(W[(size_t)orow * 128 + oc]);
        } else if (b2_ < 448) {
            int o = (b2_ - 192) * 256 + t;
            int oc = o >> 7, orow = o & 127;
            W1t[o] = f2bf(W1[(size_t)orow * 512 + oc]);
        } else {
            int o = (b2_ - 448) * 256 + t;
            int oc = o >> 9, orow = o & 511;
            W2t[o] = f2bf(W2[(size_t)orow * 128 + oc]);
        }
    }
}

// ---------------- CSR build ----------------

__global__ void count_kernel(const int* __restrict__ dst, int* counts, int E) {
    int e = blockIdx.x * blockDim.x + threadIdx.x;
    if (e < E) atomicAdd(&counts[dst[e]], 1);
}

__global__ __launch_bounds__(256) void scanA_kernel(const int* __restrict__ counts, int* bsum, int Nn) {
    int blk = blockIdx.x, t = threadIdx.x;
    int i = blk * 1024 + t * 4;
    int s = 0;
    if (i < Nn) { int4 x = *(const int4*)(counts + i); s = x.x + x.y + x.z + x.w; }
#pragma unroll
    for (int off = 1; off < 64; off <<= 1) s += __shfl_xor(s, off, 64);
    __shared__ int wt[4];
    if ((t & 63) == 0) wt[t >> 6] = s;
    __syncthreads();
    if (t == 0) bsum[blk] = wt[0] + wt[1] + wt[2] + wt[3];
}

__global__ __launch_bounds__(256) void scanC_kernel(int* counts, const int* __restrict__ bsum,
                                                    int* offsets, int Nn, int NCH) {
    int blk = blockIdx.x, t = threadIdx.x, lane = t & 63, wv = t >> 6;
    __shared__ int wt[4];
    __shared__ int base_s;
    if (wv == 0) {
        int v = (lane < NCH) ? bsum[lane] : 0;
        int s = v;
#pragma unroll
        for (int off = 1; off < 64; off <<= 1) {
            int u = __shfl_up(s, off, 64);
            if (lane >= off) s += u;
        }
        int basev = (blk > 0) ? __shfl(s, blk - 1, 64) : 0;
        int tot = __shfl(s, NCH - 1, 64);
        if (lane == 0) {
            base_s = basev;
            if (blk == 0) offsets[Nn] = tot;
        }
    }
    int i = blk * 1024 + t * 4;
    int4 x = make_int4(0, 0, 0, 0);
    if (i < Nn) x = *(const int4*)(counts + i);
    int ts = x.x + x.y + x.z + x.w;
    int s = ts;
#pragma unroll
    for (int off = 1; off < 64; off <<= 1) {
        int u = __shfl_up(s, off, 64);
        if (lane >= off) s += u;
    }
    if (lane == 63) wt[wv] = s;
    __syncthreads();
    int woff = 0;
    for (int wi = 0; wi < wv; ++wi) woff += wt[wi];
    int excl = base_s + woff + (s - ts);
    if (i < Nn) {
        int o0 = excl, o1 = o0 + x.x, o2 = o1 + x.y, o3 = o2 + x.z;
        *(int4*)(offsets + i) = make_int4(o0, o1, o2, o3);
        *(int4*)(counts + i) = make_int4(o0, o1, o2, o3);
    }
}

__global__ void fill_kernel(const int* __restrict__ dst, const int* __restrict__ src,
                            int* cursor, int* srcs, int E) {
    int e = blockIdx.x * blockDim.x + threadIdx.x;
    if (e < E) {
        int pos = atomicAdd(&cursor[dst[e]], 1);
        srcs[pos] = src[e];
    }
}

// ---------------- qkv GEMM -> f16 q (pre-scaled), fp8-packed kv table ----------------
// grid (3, MP/128): region 0:q 1:k 2:v.
// kvp word (per node, per lane l): bytes [k(2l),k(2l+1),v(2l),v(2l+1)] (e4m3)
#define QST 136
__global__ __launch_bounds__(256) void qkv_gemm(
        const unsigned short* __restrict__ A, const unsigned short* __restrict__ Bt,
        unsigned short* __restrict__ qb, unsigned short* __restrict__ kvp) {
    __shared__ unsigned short smem[128 * QST];
    unsigned short* As = smem;
    unsigned short* Bs = smem + 4096;
    int t = threadIdx.x;
    int wave = t >> 6, lane = t & 63;
    int wr = wave >> 1, wc = wave & 1;
    int lrow = lane & 15, kq = lane >> 4;
    int m0 = blockIdx.y * 128;
    int region = blockIdx.x;
    int n0 = region * 128;
    int srow = t >> 2, scol8 = (t & 3) * 8;

    f32x4 acc[4][4] = {};
    for (int k0 = 0; k0 < 128; k0 += 32) {
        gload_lds16(A + (size_t)(m0 + srow) * 128 + k0 + scol8,      As + t * 8);
        gload_lds16(A + (size_t)(m0 + 64 + srow) * 128 + k0 + scol8, As + 2048 + t * 8);
        gload_lds16(Bt + (size_t)(n0 + srow) * 128 + k0 + scol8,      Bs + t * 8);
        gload_lds16(Bt + (size_t)(n0 + 64 + srow) * 128 + k0 + scol8, Bs + 2048 + t * 8);
        __syncthreads();
        bf16x8 af[4], bfr[4];
#pragma unroll
        for (int mi = 0; mi < 4; ++mi)
            af[mi] = *(const bf16x8*)(&As[(wr * 64 + mi * 16 + lrow) * 32 + kq * 8]);
#pragma unroll
        for (int ni = 0; ni < 4; ++ni)
            bfr[ni] = *(const bf16x8*)(&Bs[(wc * 64 + ni * 16 + lrow) * 32 + kq * 8]);
#pragma unroll
        for (int mi = 0; mi < 4; ++mi)
#pragma unroll
            for (int ni = 0; ni < 4; ++ni)
                acc[mi][ni] = __builtin_amdgcn_mfma_f32_16x16x32_bf16(af[mi], bfr[ni], acc[mi][ni], 0, 0, 0);
        __syncthreads();
    }

    float scale = (region == 0) ? QSCALE : 1.f;
#pragma unroll
    for (int ni = 0; ni < 4; ++ni) {
        int col = wc * 64 + ni * 16 + lrow;
#pragma unroll
        for (int mi = 0; mi < 4; ++mi) {
#pragma unroll
            for (int r = 0; r < 4; ++r) {
                int row = wr * 64 + mi * 16 + kq * 4 + r;
                smem[row * QST + col] = f2h(acc[mi][ni][r] * scale);
            }
        }
    }
    __syncthreads();
    if (region == 0) {
        unsigned short* outp = qb + (size_t)m0 * 128;
#pragma unroll
        for (int i = 0; i < 8; ++i) {
            int chunk = i * 256 + t;
            int row = chunk >> 4, c16 = chunk & 15;
            *(float4*)(outp + (size_t)chunk * 8) = *(const float4*)(smem + row * QST + c16 * 8);
        }
    } else {
        int off = region - 1;                 // 0: k bytes, 1: v bytes
        int row = t >> 1, half = t & 1;
        unsigned short* dstp = kvp + (size_t)(m0 + row) * 128 + off;
        const unsigned short* sp = smem + row * QST;
#pragma unroll
        for (int jj = 0; jj < 32; ++jj) {
            int j = half * 32 + jj;
            float f0 = (float)__builtin_bit_cast(_Float16, sp[2 * j]);
            float f1 = (float)__builtin_bit_cast(_Float16, sp[2 * j + 1]);
            dstp[2 * j] = pk_fp8(f0, f1);
        }
    }
}

// ---------------- fused attention aggregate + residual + LN1 ----------------
// one wave per node, 2 dims/lane; ONE dword gather per edge (fp8 k pair + v pair).
// No online max: scores are tiny (sd~0.02); direct exp2 with +-30 clamp is exact softmax.
__global__ __launch_bounds__(256) void agg_ln1_kernel(
        const unsigned short* __restrict__ qb, const unsigned short* __restrict__ kvp,
        const float* __restrict__ feat,
        const int* __restrict__ srcs, const int* __restrict__ offsets,
        const float* __restrict__ g, const float* __restrict__ b,
        unsigned short* __restrict__ rstb, int n) {
    int node = blockIdx.x * 4 + (threadIdx.x >> 6);
    int lane = threadIdx.x & 63;
    if (node >= n) return;

    unsigned int qw = ((const unsigned int*)qb)[(size_t)node * 64 + lane];
    f16x2 qp = __builtin_bit_cast(f16x2, qw);
    float q0 = (float)qp.x, q1 = (float)qp.y;
    const unsigned int* kv32 = (const unsigned int*)kvp;   // node stride 64 words

    int beg = offsets[node], end = offsets[node + 1];
    float l = 0.f, a0 = 0.f, a1 = 0.f;

    int idx = beg;
    for (; idx + 8 <= end; idx += 8) {
        int s[8];
#pragma unroll
        for (int i = 0; i < 8; ++i) s[i] = srcs[idx + i];
        unsigned int w[8];
#pragma unroll
        for (int i = 0; i < 8; ++i) w[i] = kv32[(size_t)s[i] * 64 + lane];
        float sc[8];
#pragma unroll
        for (int i = 0; i < 8; ++i) {
            f32x2 kk = unpk_fp8<false>(w[i]);
            float p = fmaf(kk.x, q0, kk.y * q1);
            p += __shfl_xor(p, 1, 8);
            p += __shfl_xor(p, 2, 8);
            p += __shfl_xor(p, 4, 8);
            sc[i] = fminf(fmaxf(p, -30.f), 30.f);
        }
#pragma unroll
        for (int i = 0; i < 8; ++i) {
            float ww = fexp2(sc[i]);
            f32x2 vv = unpk_fp8<true>(w[i]);
            l += ww;
            a0 = fmaf(vv.x, ww, a0);
            a1 = fmaf(vv.y, ww, a1);
        }
    }
    for (; idx < end; ++idx) {
        int s = srcs[idx];
        unsigned int w = kv32[(size_t)s * 64 + lane];
        f32x2 kk = unpk_fp8<false>(w);
        float p = fmaf(kk.x, q0, kk.y * q1);
        p += __shfl_xor(p, 1, 8);
        p += __shfl_xor(p, 2, 8);
        p += __shfl_xor(p, 4, 8);
        float ww = fexp2(fminf(fmaxf(p, -30.f), 30.f));
        f32x2 vv = unpk_fp8<true>(w);
        l += ww;
        a0 = fmaf(vv.x, ww, a0);
        a1 = fmaf(vv.y, ww, a1);
    }

    float inv = (l > 0.f) ? 1.f / l : 0.f;
    float2 fv = *(const float2*)(feat + (size_t)node * DIM + 2 * lane);
    float x0 = a0 * inv + fv.x;
    float x1 = a1 * inv + fv.y;

    float s1 = x0 + x1;
    float s2 = x0 * x0 + x1 * x1;
#pragma unroll
    for (int off = 1; off < 64; off <<= 1) {
        s1 += __shfl_xor(s1, off, 64);
        s2 += __shfl_xor(s2, off, 64);
    }
    float mean = s1 * (1.f / DIM);
    float var = s2 * (1.f / DIM) - mean * mean;
    float rinv = rsqrtf(var + LN_EPS);
    float g0 = g[2 * lane], g1 = g[2 * lane + 1];
    float b0 = b[2 * lane], b1 = b[2 * lane + 1];
    float o0 = (x0 - mean) * rinv * g0 + b0;
    float o1 = (x1 - mean) * rinv * g1 + b1;
    unsigned int packed = (unsigned int)f2bf(o0) | ((unsigned int)f2bf(o1) << 16);
    ((unsigned int*)rstb)[(size_t)node * 64 + lane] = packed;
}

// ---------------- FFN1: hid = PReLU(rst @ W1 + b1), bf16 out ----------------
// grid (4, MP/128); m97-style 128x128 tile, K=128; LDS-staged coalesced stores
__global__ __launch_bounds__(256) void ffn1_gemm(
        const unsigned short* __restrict__ A, const unsigned short* __restrict__ Bt,
        unsigned short* __restrict__ hid,
        const float* __restrict__ b1, const float* __restrict__ prelu) {
    __shared__ unsigned short smem[128 * QST];
    unsigned short* As = smem;
    unsigned short* Bs = smem + 4096;
    int t = threadIdx.x;
    int wave = t >> 6, lane = t & 63;
    int wr = wave >> 1, wc = wave & 1;
    int lrow = lane & 15, kq = lane >> 4;
    int m0 = blockIdx.y * 128;
    int n0 = blockIdx.x * 128;
    int srow = t >> 2, scol8 = (t & 3) * 8;

    f32x4 acc[4][4] = {};
    for (int k0 = 0; k0 < 128; k0 += 32) {
        gload_lds16(A + (size_t)(m0 + srow) * 128 + k0 + scol8,      As + t * 8);
        gload_lds16(A + (size_t)(m0 + 64 + srow) * 128 + k0 + scol8, As + 2048 + t * 8);
        gload_lds16(Bt + (size_t)(n0 + srow) * 128 + k0 + scol8,      Bs + t * 8);
        gload_lds16(Bt + (size_t)(n0 + 64 + srow) * 128 + k0 + scol8, Bs + 2048 + t * 8);
        __syncthreads();
        bf16x8 af[4], bfr[4];
#pragma unroll
        for (int mi = 0; mi < 4; ++mi)
            af[mi] = *(const bf16x8*)(&As[(wr * 64 + mi * 16 + lrow) * 32 + kq * 8]);
#pragma unroll
        for (int ni = 0; ni < 4; ++ni)
            bfr[ni] = *(const bf16x8*)(&Bs[(wc * 64 + ni * 16 + lrow) * 32 + kq * 8]);
#pragma unroll
        for (int mi = 0; mi < 4; ++mi)
#pragma unroll
            for (int ni = 0; ni < 4; ++ni)
                acc[mi][ni] = __builtin_amdgcn_mfma_f32_16x16x32_bf16(af[mi], bfr[ni], acc[mi][ni], 0, 0, 0);
        __syncthreads();
    }

#pragma unroll
    for (int ni = 0; ni < 4; ++ni) {
        int col = wc * 64 + ni * 16 + lrow;
        int cg = n0 + col;
        float biv = b1[cg], pwv = prelu[cg];
#pragma unroll
        for (int mi = 0; mi < 4; ++mi) {
#pragma unroll
            for (int r = 0; r < 4; ++r) {
                int row = wr * 64 + mi * 16 + kq * 4 + r;
                float v = acc[mi][ni][r] + biv;
                v = v >= 0.f ? v : pwv * v;
                smem[row * QST + col] = f2bf(v);
            }
        }
    }
    __syncthreads();
#pragma unroll
    for (int i = 0; i < 8; ++i) {
        int chunk = i * 256 + t;
        int row = chunk >> 4, c16 = chunk & 15;
        *(float4*)(hid + (size_t)(m0 + row) * 512 + n0 + c16 * 8) =
            *(const float4*)(smem + row * QST + c16 * 8);
    }
}

// ---------------- FFN2 + residual + LN2: out = LN(hid @ W2 + b2 + rst) ----------------
// grid (MP/64): 64-row tiles; wave w owns cols [w*32, w*32+32).
// Epilogue: race-free two-phase reduction (redS/redQ separate, one barrier).
__global__ __launch_bounds__(256) void ffn2_ln2_kernel(
        const unsigned short* __restrict__ hid, const unsigned short* __restrict__ W2t,
        const unsigned short* __restrict__ rstb,
        const float* __restrict__ b2, const float* __restrict__ g, const float* __restrict__ bb,
        float* __restrict__ out, int Nn) {
    __shared__ unsigned short As[64 * 32];    // 4KB
    __shared__ unsigned short Bs[128 * 32];   // 8KB
    __shared__ float redS[64][4];
    __shared__ float redQ[64][4];
    int t = threadIdx.x;
    int wave = t >> 6, lane = t & 63;
    int lrow = lane & 15, kq = lane >> 4;
    int m0 = blockIdx.x * 64;
    int srow = t >> 2, scol8 = (t & 3) * 8;

    f32x4 acc[4][2] = {};
    for (int k0 = 0; k0 < 512; k0 += 32) {
        gload_lds16(hid + (size_t)(m0 + srow) * 512 + k0 + scol8, As + t * 8);
        gload_lds16(W2t + (size_t)srow * 512 + k0 + scol8,        Bs + t * 8);
        gload_lds16(W2t + (size_t)(64 + srow) * 512 + k0 + scol8, Bs + 2048 + t * 8);
        __syncthreads();
        bf16x8 af[4], bfr[2];
#pragma unroll
        for (int mi = 0; mi < 4; ++mi)
            af[mi] = *(const bf16x8*)(&As[(mi * 16 + lrow) * 32 + kq * 8]);
#pragma unroll
        for (int ni = 0; ni < 2; ++ni)
            bfr[ni] = *(const bf16x8*)(&Bs[(wave * 32 + ni * 16 + lrow) * 32 + kq * 8]);
#pragma unroll
        for (int mi = 0; mi < 4; ++mi)
#pragma unroll
            for (int ni = 0; ni < 2; ++ni)
                acc[mi][ni] = __builtin_amdgcn_mfma_f32_16x16x32_bf16(af[mi], bfr[ni], acc[mi][ni], 0, 0, 0);
        __syncthreads();
    }

    float b2v[2], gv[2], bv[2];
    int cols[2];
#pragma unroll
    for (int ni = 0; ni < 2; ++ni) {
        cols[ni] = wave * 32 + ni * 16 + lrow;
        b2v[ni] = b2[cols[ni]]; gv[ni] = g[cols[ni]]; bv[ni] = bb[cols[ni]];
    }
    // phase 1: residual add + per-wave partial reductions for all 64 rows
#pragma unroll
    for (int mi = 0; mi < 4; ++mi) {
#pragma unroll
        for (int r = 0; r < 4; ++r) {
            int rloc = mi * 16 + kq * 4 + r;
            int row = m0 + rloc;
            float ps = 0.f, pq = 0.f;
#pragma unroll
            for (int ni = 0; ni < 2; ++ni) {
                float rsv = bf2f(rstb[(size_t)row * 128 + cols[ni]]);
                float v = acc[mi][ni][r] + b2v[ni] + rsv;
                acc[mi][ni][r] = v;
                ps += v; pq += v * v;
            }
#pragma unroll
            for (int off = 1; off < 16; off <<= 1) {
                ps += __shfl_xor(ps, off, 16);
                pq += __shfl_xor(pq, off, 16);
            }
            if (lrow == 0) { redS[rloc][wave] = ps; redQ[rloc][wave] = pq; }
        }
    }
    __syncthreads();
    // phase 2: combine across waves, LN, store
#pragma unroll
    for (int mi = 0; mi < 4; ++mi) {
#pragma unroll
        for (int r = 0; r < 4; ++r) {
            int rloc = mi * 16 + kq * 4 + r;
            int row = m0 + rloc;
            float s1 = redS[rloc][0] + redS[rloc][1] + redS[rloc][2] + redS[rloc][3];
            float sq = redQ[rloc][0] + redQ[rloc][1] + redQ[rloc][2] + redQ[rloc][3];
            float mean = s1 * (1.f / DIM);
            float var = sq * (1.f / DIM) - mean * mean;
            float rs = rsqrtf(var + LN_EPS);
            if (row < Nn) {
#pragma unroll
                for (int ni = 0; ni < 2; ++ni)
                    out[(size_t)row * 128 + cols[ni]] =
                        (acc[mi][ni][r] - mean) * rs * gv[ni] + bv[ni];
            }
        }
    }
}

// ---------------- launch ----------------

extern "C" void kernel_launch(void* const* d_in, const int* in_sizes, int n_in,
                              void* d_out, int out_size, void* d_ws, size_t ws_size,
                              hipStream_t stream) {
    const float* feat   = (const float*)d_in[0];
    const int*   src    = (const int*)d_in[1];
    const int*   dst    = (const int*)d_in[2];
    const float* Wq     = (const float*)d_in[3];
    const float* Wk     = (const float*)d_in[4];
    const float* Wv     = (const float*)d_in[5];
    const float* ln1_g  = (const float*)d_in[6];
    const float* ln1_b  = (const float*)d_in[7];
    const float* ln2_g  = (const float*)d_in[8];
    const float* ln2_b  = (const float*)d_in[9];
    const float* W1     = (const float*)d_in[10];
    const float* b1     = (const float*)d_in[11];
    const float* prelu  = (const float*)d_in[12];
    const float* W2     = (const float*)d_in[13];
    const float* b2     = (const float*)d_in[14];
    float* out = (float*)d_out;

    const int Nn = in_sizes[0] / DIM;        // 40000
    const int E  = in_sizes[1];              // 640000
    const int MP = (Nn + 127) & ~127;        // 40064

    char* w = (char*)d_ws;
    unsigned short* qb   = (unsigned short*)w; w += (size_t)MP * DIM * 2;
    unsigned short* kvp  = (unsigned short*)w; w += (size_t)MP * DIM * 2;  // fp8-packed k|v
    unsigned short* rstb = (unsigned short*)w; w += (size_t)MP * DIM * 2;
    unsigned short* featb= (unsigned short*)w; w += (size_t)MP * DIM * 2;
    unsigned short* hid  = (unsigned short*)w; w += (size_t)MP * HID * 2;
    unsigned short* Wqkvt= (unsigned short*)w; w += 3 * DIM * DIM * 2;
    unsigned short* W1t  = (unsigned short*)w; w += (size_t)HID * DIM * 2;
    unsigned short* W2t  = (unsigned short*)w; w += (size_t)DIM * HID * 2;
    int* counts  = (int*)w;  w += (size_t)Nn * 4;
    int* offsets = (int*)w;  w += (size_t)(Nn + 4) * 4;
    int* bsum    = (int*)w;  w += 64 * 4;
    int* srcs    = (int*)w;

    const int NCH = (Nn + 1023) / 1024;      // 40 (<= 64)
    const int zb = NCH;
    const int fb = zb + Nn / 8;

    prep_kernel<<<fb + 192 + 256 + 256, 256, 0, stream>>>(
        counts, Nn, feat, featb, Wq, Wk, Wv, Wqkvt, W1, W1t, W2, W2t, zb, fb);

    count_kernel<<<(E + 255) / 256, 256, 0, stream>>>(dst, counts, E);
    scanA_kernel<<<NCH, 256, 0, stream>>>(counts, bsum, Nn);
    scanC_kernel<<<NCH, 256, 0, stream>>>(counts, bsum, offsets, Nn, NCH);
    fill_kernel<<<(E + 255) / 256, 256, 0, stream>>>(dst, src, counts, srcs, E);

    {
        dim3 grid(3, MP / 128);
        qkv_gemm<<<grid, 256, 0, stream>>>(featb, Wqkvt, qb, kvp);
    }

    agg_ln1_kernel<<<(Nn + 3) / 4, 256, 0, stream>>>(qb, kvp, feat, srcs, offsets,
                                                     ln1_g, ln1_b, rstb, Nn);

    {
        dim3 grid(4, MP / 128);
        ffn1_gemm<<<grid, 256, 0, stream>>>(rstb, W1t, hid, b1, prelu);
    }

    ffn2_ln2_kernel<<<MP / 64, 256, 0, stream>>>(hid, W2t, rstb, b2, ln2_g, ln2_b, out, Nn);
}

// Round 10
// 258.657 us; speedup vs baseline: 1.0849x; 1.0796x over previous
//
#include <hip/hip_runtime.h>
#include <hip/hip_bf16.h>
#include <math.h>

#define DIM 128
#define NHEAD 8
#define DHEAD 16
#define HID 512
#define LN_EPS 1e-5f
// (1/sqrt(128))*log2(e) folded into q so softmax runs in exp2 domain
#define QSCALE 0.12751879104863297f

typedef __bf16 bf16x8 __attribute__((ext_vector_type(8)));
typedef float f32x4 __attribute__((ext_vector_type(4)));
typedef float f32x2 __attribute__((ext_vector_type(2)));
typedef _Float16 f16x2 __attribute__((ext_vector_type(2)));

__device__ inline float bf2f(unsigned int bits16) {
    return __uint_as_float(bits16 << 16);
}
__device__ inline unsigned short f2bf(float f) {
    unsigned int u = __float_as_uint(f);
    unsigned int r = u + 0x7fff + ((u >> 16) & 1);   // RNE
    return (unsigned short)(r >> 16);
}
__device__ inline unsigned short f2h(float f) {
    _Float16 h = (_Float16)f;
    return __builtin_bit_cast(unsigned short, h);
}
__device__ inline float h2f(unsigned short h) {
    return (float)__builtin_bit_cast(_Float16, h);
}
// pack two floats -> two OCP e4m3 bytes (low ushort)
__device__ inline unsigned short pk_fp8(float a, float b) {
    int r = __builtin_amdgcn_cvt_pk_fp8_f32(a, b, 0, false);
    return (unsigned short)(r & 0xffff);
}
// unpack 2 fp8 bytes from low halfword
__device__ inline f32x2 unpk_fp8_lo(unsigned int w) {
    return __builtin_amdgcn_cvt_pk_f32_fp8((int)w, false);
}
__device__ inline float fexp2(float x) { return __builtin_amdgcn_exp2f(x); }

// async global->LDS, 16B per lane
__device__ inline void gload_lds16(const void* g, void* l) {
    __builtin_amdgcn_global_load_lds(
        (const __attribute__((address_space(1))) unsigned int*)g,
        (__attribute__((address_space(3))) unsigned int*)l, 16, 0, 0);
}

// ---------------- k1: prep (feat->bf16, weight transposes) + count atomics ----------------
// counts zeroed by hipMemsetAsync before this kernel.
// blocks: [0,fb) featb | [fb,fb+192) Wqkv | +256 W1t | +256 W2t | [wb, wb+cb) count
__global__ __launch_bounds__(256) void prep_count_kernel(
        int* counts, int Nn,
        const float* __restrict__ feat, unsigned short* __restrict__ featb,
        const float* __restrict__ Wq, const float* __restrict__ Wk, const float* __restrict__ Wv,
        unsigned short* __restrict__ Wqkvt,
        const float* __restrict__ W1, unsigned short* __restrict__ W1t,
        const float* __restrict__ W2, unsigned short* __restrict__ W2t,
        const int* __restrict__ dst, int E, int fb, int wb) {
    int blk = blockIdx.x, t = threadIdx.x;
    if (blk < fb) {
        int i = blk * 256 + t;            // quad index
        if (i < Nn * 32) {
            float4 v = *(const float4*)(feat + (size_t)i * 4);
            ushort4 o;
            o.x = f2bf(v.x); o.y = f2bf(v.y); o.z = f2bf(v.z); o.w = f2bf(v.w);
            *(ushort4*)(featb + (size_t)i * 4) = o;
        }
    } else if (blk < wb) {
        int b2_ = blk - fb;
        if (b2_ < 192) {
            int sec = b2_ >> 6;
            const float* W = sec == 0 ? Wq : (sec == 1 ? Wk : Wv);
            int o = (b2_ & 63) * 256 + t;
            int oc = o >> 7, orow = o & 127;
            Wqkvt[sec * 16384 + o] = f2bf(W[(size_t)orow * 128 + oc]);
        } else if (b2_ < 448) {
            int o = (b2_ - 192) * 256 + t;
            int oc = o >> 7, orow = o & 127;
            W1t[o] = f2bf(W1[(size_t)orow * 512 + oc]);
        } else {
            int o = (b2_ - 448) * 256 + t;
            int oc = o >> 9, orow = o & 511;
            W2t[o] = f2bf(W2[(size_t)orow * 128 + oc]);
        }
    } else {
        int e0 = (blk - wb) * 1024 + t * 4;
        if (e0 + 3 < E) {
            int4 d = *(const int4*)(dst + e0);
            atomicAdd(&counts[d.x], 1);
            atomicAdd(&counts[d.y], 1);
            atomicAdd(&counts[d.z], 1);
            atomicAdd(&counts[d.w], 1);
        } else {
            for (int e = e0; e < E; ++e) atomicAdd(&counts[dst[e]], 1);
        }
    }
}

// ---------------- scan ----------------

__global__ __launch_bounds__(256) void scanA_kernel(const int* __restrict__ counts, int* bsum, int Nn) {
    int blk = blockIdx.x, t = threadIdx.x;
    int i = blk * 1024 + t * 4;
    int s = 0;
    if (i < Nn) { int4 x = *(const int4*)(counts + i); s = x.x + x.y + x.z + x.w; }
#pragma unroll
    for (int off = 1; off < 64; off <<= 1) s += __shfl_xor(s, off, 64);
    __shared__ int wt[4];
    if ((t & 63) == 0) wt[t >> 6] = s;
    __syncthreads();
    if (t == 0) bsum[blk] = wt[0] + wt[1] + wt[2] + wt[3];
}

__global__ __launch_bounds__(256) void scanC_kernel(int* counts, const int* __restrict__ bsum,
                                                    int* offsets, int Nn, int NCH) {
    int blk = blockIdx.x, t = threadIdx.x, lane = t & 63, wv = t >> 6;
    __shared__ int wt[4];
    __shared__ int base_s;
    if (wv == 0) {
        int v = (lane < NCH) ? bsum[lane] : 0;
        int s = v;
#pragma unroll
        for (int off = 1; off < 64; off <<= 1) {
            int u = __shfl_up(s, off, 64);
            if (lane >= off) s += u;
        }
        int basev = (blk > 0) ? __shfl(s, blk - 1, 64) : 0;
        int tot = __shfl(s, NCH - 1, 64);
        if (lane == 0) {
            base_s = basev;
            if (blk == 0) offsets[Nn] = tot;
        }
    }
    int i = blk * 1024 + t * 4;
    int4 x = make_int4(0, 0, 0, 0);
    if (i < Nn) x = *(const int4*)(counts + i);
    int ts = x.x + x.y + x.z + x.w;
    int s = ts;
#pragma unroll
    for (int off = 1; off < 64; off <<= 1) {
        int u = __shfl_up(s, off, 64);
        if (lane >= off) s += u;
    }
    if (lane == 63) wt[wv] = s;
    __syncthreads();
    int woff = 0;
    for (int wi = 0; wi < wv; ++wi) woff += wt[wi];
    int excl = base_s + woff + (s - ts);
    if (i < Nn) {
        int o0 = excl, o1 = o0 + x.x, o2 = o1 + x.y, o3 = o2 + x.z;
        *(int4*)(offsets + i) = make_int4(o0, o1, o2, o3);
        *(int4*)(counts + i) = make_int4(o0, o1, o2, o3);
    }
}

// ---------------- k4: fill (CSR scatter) + qkv GEMM ----------------
// blocks [0, cb): fill; blocks [cb, cb+3*MB): qkv (region = q%3, mtile = q/3)
// q: f16 pre-scaled [node][128]. kv8: per node 256B = 128B k-fp8 | 128B v-fp8.
#define QST 136
__global__ __launch_bounds__(256) void fill_qkv_kernel(
        const int* __restrict__ dst, const int* __restrict__ src,
        int* cursor, int* srcs, int E, int cb,
        const unsigned short* __restrict__ A, const unsigned short* __restrict__ Bt,
        unsigned short* __restrict__ qb, unsigned char* __restrict__ kv8) {
    int blk = blockIdx.x, t = threadIdx.x;
    if (blk < cb) {
        int e0 = blk * 1024 + t * 4;
        if (e0 + 3 < E) {
            int4 d = *(const int4*)(dst + e0);
            int4 sv = *(const int4*)(src + e0);
            srcs[atomicAdd(&cursor[d.x], 1)] = sv.x;
            srcs[atomicAdd(&cursor[d.y], 1)] = sv.y;
            srcs[atomicAdd(&cursor[d.z], 1)] = sv.z;
            srcs[atomicAdd(&cursor[d.w], 1)] = sv.w;
        } else {
            for (int e = e0; e < E; ++e) srcs[atomicAdd(&cursor[dst[e]], 1)] = src[e];
        }
        return;
    }
    __shared__ unsigned short smem[128 * QST];
    unsigned short* As = smem;
    unsigned short* Bs = smem + 4096;
    int q = blk - cb;
    int region = q % 3;
    int m0 = (q / 3) * 128;
    int wave = t >> 6, lane = t & 63;
    int wr = wave >> 1, wc = wave & 1;
    int lrow = lane & 15, kq = lane >> 4;
    int n0 = region * 128;
    int srow = t >> 2, scol8 = (t & 3) * 8;

    f32x4 acc[4][4] = {};
    for (int k0 = 0; k0 < 128; k0 += 32) {
        gload_lds16(A + (size_t)(m0 + srow) * 128 + k0 + scol8,      As + t * 8);
        gload_lds16(A + (size_t)(m0 + 64 + srow) * 128 + k0 + scol8, As + 2048 + t * 8);
        gload_lds16(Bt + (size_t)(n0 + srow) * 128 + k0 + scol8,      Bs + t * 8);
        gload_lds16(Bt + (size_t)(n0 + 64 + srow) * 128 + k0 + scol8, Bs + 2048 + t * 8);
        __syncthreads();
        bf16x8 af[4], bfr[4];
#pragma unroll
        for (int mi = 0; mi < 4; ++mi)
            af[mi] = *(const bf16x8*)(&As[(wr * 64 + mi * 16 + lrow) * 32 + kq * 8]);
#pragma unroll
        for (int ni = 0; ni < 4; ++ni)
            bfr[ni] = *(const bf16x8*)(&Bs[(wc * 64 + ni * 16 + lrow) * 32 + kq * 8]);
#pragma unroll
        for (int mi = 0; mi < 4; ++mi)
#pragma unroll
            for (int ni = 0; ni < 4; ++ni)
                acc[mi][ni] = __builtin_amdgcn_mfma_f32_16x16x32_bf16(af[mi], bfr[ni], acc[mi][ni], 0, 0, 0);
        __syncthreads();
    }

    float scale = (region == 0) ? QSCALE : 1.f;
#pragma unroll
    for (int ni = 0; ni < 4; ++ni) {
        int col = wc * 64 + ni * 16 + lrow;
#pragma unroll
        for (int mi = 0; mi < 4; ++mi) {
#pragma unroll
            for (int r = 0; r < 4; ++r) {
                int row = wr * 64 + mi * 16 + kq * 4 + r;
                smem[row * QST + col] = f2h(acc[mi][ni][r] * scale);
            }
        }
    }
    __syncthreads();
    if (region == 0) {
        unsigned short* outp = qb + (size_t)m0 * 128;
#pragma unroll
        for (int i = 0; i < 8; ++i) {
            int chunk = i * 256 + t;
            int row = chunk >> 4, c16 = chunk & 15;
            *(float4*)(outp + (size_t)chunk * 8) = *(const float4*)(smem + row * QST + c16 * 8);
        }
    } else {
        // fp8 convert + coalesced 16B stores: 128 rows x 8 chunks of 16 dims
        int half = region - 1;   // 0:k, 1:v
#pragma unroll
        for (int i = 0; i < 4; ++i) {
            int chunk = i * 256 + t;         // 0..1023
            int row = chunk >> 3, seg = chunk & 7;
            const unsigned short* sp = smem + row * QST + seg * 16;
            unsigned int ow[4];
#pragma unroll
            for (int j = 0; j < 4; ++j) {
                unsigned int lo = pk_fp8(h2f(sp[4 * j]), h2f(sp[4 * j + 1]));
                unsigned int hi = pk_fp8(h2f(sp[4 * j + 2]), h2f(sp[4 * j + 3]));
                ow[j] = lo | (hi << 16);
            }
            *(uint4*)(kv8 + (size_t)(m0 + row) * 256 + half * 128 + seg * 16) =
                make_uint4(ow[0], ow[1], ow[2], ow[3]);
        }
    }
}

// ---------------- k5: fused attention aggregate + residual + LN1 ----------------
// one wave per node, 2 dims/lane; fp8 k/v in kv8 (two ushort gathers per edge).
// Uniform masked 8-chunks: invalid slots get sc=-1000 -> exp2=0 (no scalar tail).
__global__ __launch_bounds__(256) void agg_ln1_kernel(
        const unsigned short* __restrict__ qb, const unsigned short* __restrict__ kvu,
        const float* __restrict__ feat,
        const int* __restrict__ srcs, const int* __restrict__ offsets,
        const float* __restrict__ g, const float* __restrict__ b,
        unsigned short* __restrict__ rstb, int n) {
    int node = blockIdx.x * 4 + (threadIdx.x >> 6);
    int lane = threadIdx.x & 63;
    if (node >= n) return;

    unsigned int qw = ((const unsigned int*)qb)[(size_t)node * 64 + lane];
    f16x2 qp = __builtin_bit_cast(f16x2, qw);
    float q0 = (float)qp.x, q1 = (float)qp.y;

    int beg = offsets[node], end = offsets[node + 1];
    float l = 0.f, a0 = 0.f, a1 = 0.f;

    for (int idx = beg; idx < end; idx += 8) {
        int sa[8];
#pragma unroll
        for (int i = 0; i < 8; ++i) {
            int ii = idx + i;
            sa[i] = (ii < end) ? srcs[ii] : -1;
        }
        unsigned int kw[8], vw[8];
#pragma unroll
        for (int i = 0; i < 8; ++i) {
            int s = sa[i] < 0 ? 0 : sa[i];
            kw[i] = kvu[(size_t)s * 128 + lane];
        }
#pragma unroll
        for (int i = 0; i < 8; ++i) {
            int s = sa[i] < 0 ? 0 : sa[i];
            vw[i] = kvu[(size_t)s * 128 + 64 + lane];
        }
        float sc[8];
#pragma unroll
        for (int i = 0; i < 8; ++i) {
            f32x2 kk = unpk_fp8_lo(kw[i]);
            float p = fmaf(kk.x, q0, kk.y * q1);
            p += __shfl_xor(p, 1, 8);
            p += __shfl_xor(p, 2, 8);
            p += __shfl_xor(p, 4, 8);
            p = fminf(fmaxf(p, -30.f), 30.f);
            sc[i] = (sa[i] < 0) ? -1000.f : p;
        }
#pragma unroll
        for (int i = 0; i < 8; ++i) {
            float ww = fexp2(sc[i]);
            f32x2 vv = unpk_fp8_lo(vw[i]);
            l += ww;
            a0 = fmaf(vv.x, ww, a0);
            a1 = fmaf(vv.y, ww, a1);
        }
    }

    float inv = (l > 0.f) ? 1.f / l : 0.f;
    float2 fv = *(const float2*)(feat + (size_t)node * DIM + 2 * lane);
    float x0 = a0 * inv + fv.x;
    float x1 = a1 * inv + fv.y;

    float s1 = x0 + x1;
    float s2 = x0 * x0 + x1 * x1;
#pragma unroll
    for (int off = 1; off < 64; off <<= 1) {
        s1 += __shfl_xor(s1, off, 64);
        s2 += __shfl_xor(s2, off, 64);
    }
    float mean = s1 * (1.f / DIM);
    float var = s2 * (1.f / DIM) - mean * mean;
    float rinv = rsqrtf(var + LN_EPS);
    float g0 = g[2 * lane], g1 = g[2 * lane + 1];
    float b0 = b[2 * lane], b1 = b[2 * lane + 1];
    float o0 = (x0 - mean) * rinv * g0 + b0;
    float o1 = (x1 - mean) * rinv * g1 + b1;
    unsigned int packed = (unsigned int)f2bf(o0) | ((unsigned int)f2bf(o1) << 16);
    ((unsigned int*)rstb)[(size_t)node * 64 + lane] = packed;
}

// ---------------- k6: FFN1: hid = PReLU(rst @ W1 + b1), bf16 out ----------------
__global__ __launch_bounds__(256) void ffn1_gemm(
        const unsigned short* __restrict__ A, const unsigned short* __restrict__ Bt,
        unsigned short* __restrict__ hid,
        const float* __restrict__ b1, const float* __restrict__ prelu) {
    __shared__ unsigned short smem[128 * QST];
    unsigned short* As = smem;
    unsigned short* Bs = smem + 4096;
    int t = threadIdx.x;
    int wave = t >> 6, lane = t & 63;
    int wr = wave >> 1, wc = wave & 1;
    int lrow = lane & 15, kq = lane >> 4;
    int m0 = blockIdx.y * 128;
    int n0 = blockIdx.x * 128;
    int srow = t >> 2, scol8 = (t & 3) * 8;

    f32x4 acc[4][4] = {};
    for (int k0 = 0; k0 < 128; k0 += 32) {
        gload_lds16(A + (size_t)(m0 + srow) * 128 + k0 + scol8,      As + t * 8);
        gload_lds16(A + (size_t)(m0 + 64 + srow) * 128 + k0 + scol8, As + 2048 + t * 8);
        gload_lds16(Bt + (size_t)(n0 + srow) * 128 + k0 + scol8,      Bs + t * 8);
        gload_lds16(Bt + (size_t)(n0 + 64 + srow) * 128 + k0 + scol8, Bs + 2048 + t * 8);
        __syncthreads();
        bf16x8 af[4], bfr[4];
#pragma unroll
        for (int mi = 0; mi < 4; ++mi)
            af[mi] = *(const bf16x8*)(&As[(wr * 64 + mi * 16 + lrow) * 32 + kq * 8]);
#pragma unroll
        for (int ni = 0; ni < 4; ++ni)
            bfr[ni] = *(const bf16x8*)(&Bs[(wc * 64 + ni * 16 + lrow) * 32 + kq * 8]);
#pragma unroll
        for (int mi = 0; mi < 4; ++mi)
#pragma unroll
            for (int ni = 0; ni < 4; ++ni)
                acc[mi][ni] = __builtin_amdgcn_mfma_f32_16x16x32_bf16(af[mi], bfr[ni], acc[mi][ni], 0, 0, 0);
        __syncthreads();
    }

#pragma unroll
    for (int ni = 0; ni < 4; ++ni) {
        int col = wc * 64 + ni * 16 + lrow;
        int cg = n0 + col;
        float biv = b1[cg], pwv = prelu[cg];
#pragma unroll
        for (int mi = 0; mi < 4; ++mi) {
#pragma unroll
            for (int r = 0; r < 4; ++r) {
                int row = wr * 64 + mi * 16 + kq * 4 + r;
                float v = acc[mi][ni][r] + biv;
                v = v >= 0.f ? v : pwv * v;
                smem[row * QST + col] = f2bf(v);
            }
        }
    }
    __syncthreads();
#pragma unroll
    for (int i = 0; i < 8; ++i) {
        int chunk = i * 256 + t;
        int row = chunk >> 4, c16 = chunk & 15;
        *(float4*)(hid + (size_t)(m0 + row) * 512 + n0 + c16 * 8) =
            *(const float4*)(smem + row * QST + c16 * 8);
    }
}

// ---------------- k7: FFN2 + residual + LN2 ----------------
// grid (MP/64): 64-row tiles; wave w owns cols [w*32, w*32+32); two-phase LN reduction.
__global__ __launch_bounds__(256) void ffn2_ln2_kernel(
        const unsigned short* __restrict__ hid, const unsigned short* __restrict__ W2t,
        const unsigned short* __restrict__ rstb,
        const float* __restrict__ b2, const float* __restrict__ g, const float* __restrict__ bb,
        float* __restrict__ out, int Nn) {
    __shared__ unsigned short As[64 * 32];
    __shared__ unsigned short Bs[128 * 32];
    __shared__ float redS[64][4];
    __shared__ float redQ[64][4];
    int t = threadIdx.x;
    int wave = t >> 6, lane = t & 63;
    int lrow = lane & 15, kq = lane >> 4;
    int m0 = blockIdx.x * 64;
    int srow = t >> 2, scol8 = (t & 3) * 8;

    f32x4 acc[4][2] = {};
    for (int k0 = 0; k0 < 512; k0 += 32) {
        gload_lds16(hid + (size_t)(m0 + srow) * 512 + k0 + scol8, As + t * 8);
        gload_lds16(W2t + (size_t)srow * 512 + k0 + scol8,        Bs + t * 8);
        gload_lds16(W2t + (size_t)(64 + srow) * 512 + k0 + scol8, Bs + 2048 + t * 8);
        __syncthreads();
        bf16x8 af[4], bfr[2];
#pragma unroll
        for (int mi = 0; mi < 4; ++mi)
            af[mi] = *(const bf16x8*)(&As[(mi * 16 + lrow) * 32 + kq * 8]);
#pragma unroll
        for (int ni = 0; ni < 2; ++ni)
            bfr[ni] = *(const bf16x8*)(&Bs[(wave * 32 + ni * 16 + lrow) * 32 + kq * 8]);
#pragma unroll
        for (int mi = 0; mi < 4; ++mi)
#pragma unroll
            for (int ni = 0; ni < 2; ++ni)
                acc[mi][ni] = __builtin_amdgcn_mfma_f32_16x16x32_bf16(af[mi], bfr[ni], acc[mi][ni], 0, 0, 0);
        __syncthreads();
    }

    float b2v[2], gv[2], bv[2];
    int cols[2];
#pragma unroll
    for (int ni = 0; ni < 2; ++ni) {
        cols[ni] = wave * 32 + ni * 16 + lrow;
        b2v[ni] = b2[cols[ni]]; gv[ni] = g[cols[ni]]; bv[ni] = bb[cols[ni]];
    }
#pragma unroll
    for (int mi = 0; mi < 4; ++mi) {
#pragma unroll
        for (int r = 0; r < 4; ++r) {
            int rloc = mi * 16 + kq * 4 + r;
            int row = m0 + rloc;
            float ps = 0.f, pq = 0.f;
#pragma unroll
            for (int ni = 0; ni < 2; ++ni) {
                float rsv = bf2f(rstb[(size_t)row * 128 + cols[ni]]);
                float v = acc[mi][ni][r] + b2v[ni] + rsv;
                acc[mi][ni][r] = v;
                ps += v; pq += v * v;
            }
#pragma unroll
            for (int off = 1; off < 16; off <<= 1) {
                ps += __shfl_xor(ps, off, 16);
                pq += __shfl_xor(pq, off, 16);
            }
            if (lrow == 0) { redS[rloc][wave] = ps; redQ[rloc][wave] = pq; }
        }
    }
    __syncthreads();
#pragma unroll
    for (int mi = 0; mi < 4; ++mi) {
#pragma unroll
        for (int r = 0; r < 4; ++r) {
            int rloc = mi * 16 + kq * 4 + r;
            int row = m0 + rloc;
            float s1 = redS[rloc][0] + redS[rloc][1] + redS[rloc][2] + redS[rloc][3];
            float sq = redQ[rloc][0] + redQ[rloc][1] + redQ[rloc][2] + redQ[rloc][3];
            float mean = s1 * (1.f / DIM);
            float var = sq * (1.f / DIM) - mean * mean;
            float rs = rsqrtf(var + LN_EPS);
            if (row < Nn) {
#pragma unroll
                for (int ni = 0; ni < 2; ++ni)
                    out[(size_t)row * 128 + cols[ni]] =
                        (acc[mi][ni][r] - mean) * rs * gv[ni] + bv[ni];
            }
        }
    }
}

// ---------------- launch ----------------

extern "C" void kernel_launch(void* const* d_in, const int* in_sizes, int n_in,
                              void* d_out, int out_size, void* d_ws, size_t ws_size,
                              hipStream_t stream) {
    const float* feat   = (const float*)d_in[0];
    const int*   src    = (const int*)d_in[1];
    const int*   dst    = (const int*)d_in[2];
    const float* Wq     = (const float*)d_in[3];
    const float* Wk     = (const float*)d_in[4];
    const float* Wv     = (const float*)d_in[5];
    const float* ln1_g  = (const float*)d_in[6];
    const float* ln1_b  = (const float*)d_in[7];
    const float* ln2_g  = (const float*)d_in[8];
    const float* ln2_b  = (const float*)d_in[9];
    const float* W1     = (const float*)d_in[10];
    const float* b1     = (const float*)d_in[11];
    const float* prelu  = (const float*)d_in[12];
    const float* W2     = (const float*)d_in[13];
    const float* b2     = (const float*)d_in[14];
    float* out = (float*)d_out;

    const int Nn = in_sizes[0] / DIM;        // 40000
    const int E  = in_sizes[1];              // 640000
    const int MP = (Nn + 127) & ~127;        // 40064

    char* w = (char*)d_ws;
    unsigned short* qb   = (unsigned short*)w; w += (size_t)MP * DIM * 2;
    unsigned char*  kv8  = (unsigned char*)w;  w += (size_t)MP * 256;   // 128B k | 128B v per node
    unsigned short* rstb = (unsigned short*)w; w += (size_t)MP * DIM * 2;
    unsigned short* featb= (unsigned short*)w; w += (size_t)MP * DIM * 2;
    unsigned short* hid  = (unsigned short*)w; w += (size_t)MP * HID * 2;
    unsigned short* Wqkvt= (unsigned short*)w; w += 3 * DIM * DIM * 2;
    unsigned short* W1t  = (unsigned short*)w; w += (size_t)HID * DIM * 2;
    unsigned short* W2t  = (unsigned short*)w; w += (size_t)DIM * HID * 2;
    int* counts  = (int*)w;  w += (size_t)Nn * 4;
    int* offsets = (int*)w;  w += (size_t)(Nn + 4) * 4;
    int* bsum    = (int*)w;  w += 64 * 4;
    int* srcs    = (int*)w;

    const int NCH = (Nn + 1023) / 1024;      // 40 (<= 64)
    const int FB  = Nn / 8;                  // featb blocks (Nn*32 quads / 256)
    const int WB  = FB + 704;                // + weight transpose blocks
    const int CB  = (E + 1023) / 1024;       // count/fill blocks

    hipMemsetAsync(counts, 0, (size_t)Nn * 4, stream);

    prep_count_kernel<<<WB + CB, 256, 0, stream>>>(
        counts, Nn, feat, featb, Wq, Wk, Wv, Wqkvt, W1, W1t, W2, W2t, dst, E, FB, WB);

    scanA_kernel<<<NCH, 256, 0, stream>>>(counts, bsum, Nn);
    scanC_kernel<<<NCH, 256, 0, stream>>>(counts, bsum, offsets, Nn, NCH);

    fill_qkv_kernel<<<CB + 3 * (MP / 128), 256, 0, stream>>>(
        dst, src, counts, srcs, E, CB, featb, Wqkvt, qb, kv8);

    agg_ln1_kernel<<<(Nn + 3) / 4, 256, 0, stream>>>(qb, (const unsigned short*)kv8, feat,
                                                     srcs, offsets, ln1_g, ln1_b, rstb, Nn);

    {
        dim3 grid(4, MP / 128);
        ffn1_gemm<<<grid, 256, 0, stream>>>(rstb, W1t, hid, b1, prelu);
    }

    ffn2_ln2_kernel<<<MP / 64, 256, 0, stream>>>(hid, W2t, rstb, b2, ln2_g, ln2_b, out, Nn);
}